// Round 1
// baseline (664.676 us; speedup 1.0000x reference)
//
#include <hip/hip_runtime.h>
#include <hip/hip_bf16.h>

// BilinearDense: out = einsum('bz,bi,zoi->bo', z, x, Wk[z, o*256+i])
//                      + x @ W_bias[o,:] + z @ b_kernel + b_bias
// Reformulated as ONE GEMM (no 1 GB W intermediate):
//   C[b,o] = sum_k A[b,k] * Bt[o,k],  k=(zz,i), K=65536
//   A[b,k] = z[b, k>>8] * x[b, k&255]   (computed on the fly in staging)
//   Bt[o,k] = Wk_flat[(k>>8)*65536 + o*256 + (k&255)]  (contiguous 256B rows)
// Split-K=16, fp32 atomicAdd into out; init kernel writes the bias terms
// first (also serves as the d_out zero/init since harness poisons 0xAA).

#define B_DIM 4096
#define XD 256
#define ZD 256
#define OD 256

typedef __bf16 bf16x8 __attribute__((ext_vector_type(8)));
typedef float f32x4 __attribute__((ext_vector_type(4)));
typedef unsigned short us8 __attribute__((ext_vector_type(8)));

__device__ __forceinline__ unsigned short f2bf(float f) {
    union { float f; unsigned int u; } v; v.f = f;
    unsigned int r = v.u + 0x7fffu + ((v.u >> 16) & 1u);  // RNE
    return (unsigned short)(r >> 16);
}

// ---------------- init kernel: bias terms ----------------
// out[b,o] = b_bias[o] + sum_z z[b,z]*bk[z,o] + sum_i x[b,i]*Wb[o*256+i]
constexpr int IROWS = 8;

__global__ __launch_bounds__(256)
void bilinear_init(const float* __restrict__ x, const float* __restrict__ z,
                   const float* __restrict__ Wb, const float* __restrict__ bk,
                   const float* __restrict__ bb, float* __restrict__ out)
{
    __shared__ float zrow[IROWS][ZD];
    __shared__ float xrow[IROWS][XD];
    const int b0 = blockIdx.x * IROWS;
    const int o = threadIdx.x;  // 256 threads = one per output column

    #pragma unroll
    for (int r = 0; r < IROWS; ++r) {
        zrow[r][o] = z[(size_t)(b0 + r) * ZD + o];
        xrow[r][o] = x[(size_t)(b0 + r) * XD + o];
    }
    __syncthreads();

    float acc[IROWS];
    const float bbo = bb[o];
    #pragma unroll
    for (int r = 0; r < IROWS; ++r) acc[r] = bbo;

    // z @ b_kernel  (bk[z][o], coalesced across o)
    for (int zz = 0; zz < ZD; ++zz) {
        const float w = bk[(size_t)zz * OD + o];
        #pragma unroll
        for (int r = 0; r < IROWS; ++r) acc[r] += zrow[r][zz] * w;
    }

    // x @ Wb-rows  (Wb[o*256+i], contiguous per thread)
    const float4* wp = reinterpret_cast<const float4*>(Wb + (size_t)o * XD);
    for (int i4 = 0; i4 < XD / 4; ++i4) {
        const float4 w = wp[i4];
        #pragma unroll
        for (int r = 0; r < IROWS; ++r) {
            acc[r] += w.x * xrow[r][i4 * 4 + 0] + w.y * xrow[r][i4 * 4 + 1]
                    + w.z * xrow[r][i4 * 4 + 2] + w.w * xrow[r][i4 * 4 + 3];
        }
    }

    #pragma unroll
    for (int r = 0; r < IROWS; ++r)
        out[(size_t)(b0 + r) * OD + o] = acc[r];
}

// ---------------- main GEMM ----------------
constexpr int BM = 128, BN = 128, BK = 64;
constexpr int SPLITK = 16;
constexpr int KTOT = ZD * XD;        // 65536
constexpr int KCH = KTOT / SPLITK;   // 4096

__global__ __launch_bounds__(256, 2)
void bilinear_gemm(const float* __restrict__ x, const float* __restrict__ z,
                   const float* __restrict__ Wk, float* __restrict__ out)
{
    // +8 pad: row stride 144 B -> 4-bank step per row, ~2-way conflicts max
    __shared__ unsigned short Alds[BM][BK + 8];
    __shared__ unsigned short Blds[BN][BK + 8];

    const int mt = blockIdx.x;   // 0..31  (fastest-varying: all mt share B-tiles -> L2 reuse)
    const int nt = blockIdx.y;   // 0..1
    const int ks = blockIdx.z;   // 0..15  split-K
    const int m0 = mt * BM, n0 = nt * BN;

    const int t = threadIdx.x;
    const int lane = t & 63, w = t >> 6;          // 4 waves, 2x2
    const int wm = (w >> 1) * 64, wn = (w & 1) * 64;
    const int r16 = lane & 15, kg = lane >> 4;

    // staging role: thread t owns row (t>>1), k-half (t&1)*32  (32 elems of A and of B)
    const int ra = t >> 1;
    const int kh = (t & 1) * 32;

    f32x4 acc[4][4] = {};

    for (int kt = 0; kt < KCH / BK; ++kt) {
        const int k0 = ks * KCH + kt * BK;
        const int zb = k0 >> 8;    // which z column this K-chunk belongs to (BK=64 | 256)
        const int ib = k0 & 255;   // x/i base within the 256-block

        // issue global loads early (fp32)
        const float zv = z[(size_t)(m0 + ra) * ZD + zb];
        const float4* xp = reinterpret_cast<const float4*>(
            x + (size_t)(m0 + ra) * XD + ib + kh);
        const float4* bp = reinterpret_cast<const float4*>(
            Wk + (size_t)zb * (OD * XD) + (size_t)(n0 + ra) * XD + ib + kh);

        float xs[32], bs[32];
        #pragma unroll
        for (int j = 0; j < 8; ++j) {
            const float4 a = xp[j];
            const float4 b = bp[j];
            xs[4 * j + 0] = a.x; xs[4 * j + 1] = a.y; xs[4 * j + 2] = a.z; xs[4 * j + 3] = a.w;
            bs[4 * j + 0] = b.x; bs[4 * j + 1] = b.y; bs[4 * j + 2] = b.z; bs[4 * j + 3] = b.w;
        }

        __syncthreads();  // previous iteration's LDS reads complete

        #pragma unroll
        for (int j = 0; j < 4; ++j) {
            us8 av, bw;
            #pragma unroll
            for (int e = 0; e < 8; ++e) {
                av[e] = f2bf(zv * xs[8 * j + e]);  // A = z*x, one bf16 rounding
                bw[e] = f2bf(bs[8 * j + e]);
            }
            *reinterpret_cast<us8*>(&Alds[ra][kh + 8 * j]) = av;
            *reinterpret_cast<us8*>(&Blds[ra][kh + 8 * j]) = bw;
        }
        __syncthreads();

        // MFMA: 2 k-halves of 32, 4x4 fragments of 16x16 per wave (64x64 out)
        #pragma unroll
        for (int khalf = 0; khalf < 2; ++khalf) {
            bf16x8 af[4], bfr[4];
            #pragma unroll
            for (int mi = 0; mi < 4; ++mi)
                af[mi] = *reinterpret_cast<const bf16x8*>(
                    &Alds[wm + mi * 16 + r16][khalf * 32 + kg * 8]);
            #pragma unroll
            for (int ni = 0; ni < 4; ++ni)
                bfr[ni] = *reinterpret_cast<const bf16x8*>(
                    &Blds[wn + ni * 16 + r16][khalf * 32 + kg * 8]);
            #pragma unroll
            for (int mi = 0; mi < 4; ++mi) {
                #pragma unroll
                for (int ni = 0; ni < 4; ++ni)
                    acc[mi][ni] = __builtin_amdgcn_mfma_f32_16x16x32_bf16(
                        af[mi], bfr[ni], acc[mi][ni], 0, 0, 0);
            }
        }
    }

    // epilogue: split-K partial -> fp32 HW atomic add
    // D layout (16x16): row = kg*4 + r, col = r16
    #pragma unroll
    for (int mi = 0; mi < 4; ++mi) {
        #pragma unroll
        for (int ni = 0; ni < 4; ++ni) {
            #pragma unroll
            for (int r = 0; r < 4; ++r) {
                const int row = m0 + wm + mi * 16 + kg * 4 + r;
                const int col = n0 + wn + ni * 16 + r16;
                unsafeAtomicAdd(&out[(size_t)row * OD + col], acc[mi][ni][r]);
            }
        }
    }
}

extern "C" void kernel_launch(void* const* d_in, const int* in_sizes, int n_in,
                              void* d_out, int out_size, void* d_ws, size_t ws_size,
                              hipStream_t stream) {
    const float* x  = (const float*)d_in[0];
    const float* z  = (const float*)d_in[1];
    const float* Wk = (const float*)d_in[2];
    const float* Wb = (const float*)d_in[3];
    const float* bk = (const float*)d_in[4];
    const float* bb = (const float*)d_in[5];
    float* out = (float*)d_out;

    // 1) bias terms (also initializes every element of out)
    bilinear_init<<<dim3(B_DIM / IROWS), dim3(256), 0, stream>>>(x, z, Wb, bk, bb, out);
    // 2) main GEMM, split-K atomics on top
    bilinear_gemm<<<dim3(B_DIM / BM, OD / BN, SPLITK), dim3(256), 0, stream>>>(x, z, Wk, out);
}

// Round 3
// 580.075 us; speedup vs baseline: 1.1458x; 1.1458x over previous
//
#include <hip/hip_runtime.h>
#include <hip/hip_bf16.h>
#include <stdint.h>

// BilinearDense: out[b,o] = sum_{zz,i} z[b,zz] * x[b,i] * Wk[zz, o*256+i]
//                           + x @ Wb-rows + z @ bk + bb
// Refactor: out[b,o] = sum_zz z[b,zz] * P_zz[b,o],  P_zz = sum_i xbf[b,i]*Wkbf[zz,o,i]
//  -> MFMA A-operand is x (constant across zz): kept in REGISTERS, zero staging.
//  -> B (Wk) pre-converted to bf16 in ws, staged via global_load_lds (zero VALU).
//  -> z folded back per-zz with fp32 scale-accumulate (better accuracy).

#define B_DIM 4096
#define XD 256
#define ZD 256
#define OD 256

typedef __bf16 bf16x8 __attribute__((ext_vector_type(8)));
typedef float f32x4 __attribute__((ext_vector_type(4)));
typedef unsigned short us8 __attribute__((ext_vector_type(8)));

__device__ __forceinline__ unsigned short f2bf(float f) {
    union { float f; unsigned int u; } v; v.f = f;
    unsigned int r = v.u + 0x7fffu + ((v.u >> 16) & 1u);  // RNE
    return (unsigned short)(r >> 16);
}

#define GLOAD_LDS16(g, l) __builtin_amdgcn_global_load_lds(                      \
    (const __attribute__((address_space(1))) uint32_t*)(uintptr_t)(g),           \
    (__attribute__((address_space(3))) uint32_t*)(uintptr_t)(l), 16, 0, 0)

// ---------------- fp32 -> bf16 convert (exact-fit grids, 8 elems/thread) ----
__global__ __launch_bounds__(256)
void cvt_f32_bf16(const float* __restrict__ in, unsigned short* __restrict__ out) {
    const int i = blockIdx.x * 256 + threadIdx.x;
    const float4* p = reinterpret_cast<const float4*>(in) + (size_t)i * 2;
    const float4 a = p[0], b = p[1];
    us8 o;
    o[0] = f2bf(a.x); o[1] = f2bf(a.y); o[2] = f2bf(a.z); o[3] = f2bf(a.w);
    o[4] = f2bf(b.x); o[5] = f2bf(b.y); o[6] = f2bf(b.z); o[7] = f2bf(b.w);
    *reinterpret_cast<us8*>(out + (size_t)i * 8) = o;
}

// ---------------- init kernel: bias terms (also zero-inits d_out) -----------
constexpr int IROWS = 32;

__global__ __launch_bounds__(256)
void bilinear_init(const float* __restrict__ x, const float* __restrict__ z,
                   const float* __restrict__ Wb, const float* __restrict__ bk,
                   const float* __restrict__ bb, float* __restrict__ out)
{
    __shared__ float zrow[IROWS][ZD];
    __shared__ float xrow[IROWS][XD];
    const int b0 = blockIdx.x * IROWS;
    const int o = threadIdx.x;

    #pragma unroll
    for (int r = 0; r < IROWS; ++r) {
        zrow[r][o] = z[(size_t)(b0 + r) * ZD + o];
        xrow[r][o] = x[(size_t)(b0 + r) * XD + o];
    }
    __syncthreads();

    float acc[IROWS];
    const float bbo = bb[o];
    #pragma unroll
    for (int r = 0; r < IROWS; ++r) acc[r] = bbo;

    for (int zz = 0; zz < ZD; ++zz) {
        const float w = bk[(size_t)zz * OD + o];
        #pragma unroll
        for (int r = 0; r < IROWS; ++r) acc[r] += zrow[r][zz] * w;
    }

    const float4* wp = reinterpret_cast<const float4*>(Wb + (size_t)o * XD);
    for (int i4 = 0; i4 < XD / 4; ++i4) {
        const float4 w = wp[i4];
        #pragma unroll
        for (int r = 0; r < IROWS; ++r) {
            acc[r] += w.x * xrow[r][i4 * 4 + 0] + w.y * xrow[r][i4 * 4 + 1]
                    + w.z * xrow[r][i4 * 4 + 2] + w.w * xrow[r][i4 * 4 + 3];
        }
    }

    #pragma unroll
    for (int r = 0; r < IROWS; ++r)
        out[(size_t)(b0 + r) * OD + o] = acc[r];
}

// ---------------- main GEMM (bf16 path) -------------------------------------
constexpr int BM = 64, BN = 128, BKI = 128;   // BKI = i-elems per stage (half a zz)
constexpr int SZ = 8;                          // split-K chunks over zz
constexpr int ZCH = ZD / SZ;                   // 32 zz per block
constexpr int NSTEP = ZCH * 2;                 // 64 stages

__global__ __launch_bounds__(256, 2)
void bilinear_gemm2(const unsigned short* __restrict__ Wkb,  // bf16 [ZD][OD*XD]
                    const unsigned short* __restrict__ xb,   // bf16 [B][XD]
                    const float* __restrict__ z,
                    float* __restrict__ out)
{
    __shared__ __align__(16) unsigned short Blds[2][BN * BKI];  // [o-row][i] linear
    __shared__ __align__(16) float zlds[ZCH][BM];               // transposed z tile

    // XCD-chunked swizzle: 64 consecutive sw share one (nt,kc) B-stream per XCD
    const int bid = blockIdx.x;
    const int sw = (bid & 7) * 128 + (bid >> 3);
    const int mt = sw & 63;
    const int g  = sw >> 6;            // 16 groups
    const int nt = g & 1, kc = g >> 1;
    const int bm0 = mt * BM, n0 = nt * BN, zb0 = kc * ZCH;

    const int t = threadIdx.x, lane = t & 63, w = t >> 6;
    const int wr = w >> 1, wc = w & 1;           // wave tile: 32 m x 64 n
    const int r16 = lane & 15, kg = lane >> 4;

    // ---- stage z tile transposed: zlds[zz][row] ----
    {
        const int row = t >> 2, q = t & 3;
        const float4* zp = reinterpret_cast<const float4*>(
            z + (size_t)(bm0 + row) * ZD + zb0 + q * 8);
        const float4 a = zp[0], b = zp[1];
        float v[8] = {a.x, a.y, a.z, a.w, b.x, b.y, b.z, b.w};
        #pragma unroll
        for (int e = 0; e < 8; ++e) zlds[q * 8 + e][row] = v[e];
    }

    // ---- x fragments in registers (constant across all zz) ----
    // 16x16x32 A-frag: lane holds A[row = base + (l&15)][k = (l>>4)*8 + e]
    bf16x8 xf[2][8];
    #pragma unroll
    for (int mi = 0; mi < 2; ++mi) {
        const int row = bm0 + wr * 32 + mi * 16 + r16;
        #pragma unroll
        for (int ks = 0; ks < 8; ++ks)
            xf[mi][ks] = *reinterpret_cast<const bf16x8*>(
                xb + (size_t)row * XD + ks * 32 + kg * 8);
    }

    // ---- B stage: 32 KB tile = 128 o-rows x 128 i (bf16), linear LDS ----
    auto stageB = [&](int s, int buf) {
        const int zz = zb0 + (s >> 1), ih = s & 1;
        const size_t srcBase = (size_t)zz * (OD * XD) + (size_t)n0 * XD + ih * BKI;
        #pragma unroll
        for (int j = 0; j < 8; ++j) {
            const int offu = w * 8192 + j * 1024;          // wave-uniform byte base
            const int off  = offu + lane * 16;             // this lane's bytes
            const int row  = off >> 8;                     // 256 B per row
            const int cole = (off & 255) >> 1;             // element col in row
            const unsigned short* src = Wkb + srcBase + (size_t)row * XD + cole;
            unsigned short* dst = &Blds[buf][0] + (offu >> 1);
            GLOAD_LDS16(src, dst);
        }
    };

    const f32x4 vzero = {0.f, 0.f, 0.f, 0.f};
    f32x4 accP[2][4] = {};
    f32x4 accO[2][4] = {};

    stageB(0, 0);
    __syncthreads();

    int buf = 0;
    for (int s = 0; s < NSTEP; ++s) {
        if (s + 1 < NSTEP) stageB(s + 1, buf ^ 1);  // prefetch next stage

        const int ih = s & 1;
        const unsigned short* bp = &Blds[buf][0];
        #pragma unroll
        for (int ks = 0; ks < 4; ++ks) {
            bf16x8 bfv[4];
            #pragma unroll
            for (int ni = 0; ni < 4; ++ni) {
                const int row = wc * 64 + ni * 16 + r16;
                bfv[ni] = *reinterpret_cast<const bf16x8*>(
                    bp + row * BKI + ks * 32 + kg * 16 / 2);
            }
            #pragma unroll
            for (int mi = 0; mi < 2; ++mi)
                #pragma unroll
                for (int ni = 0; ni < 4; ++ni)
                    accP[mi][ni] = __builtin_amdgcn_mfma_f32_16x16x32_bf16(
                        xf[mi][ih * 4 + ks], bfv[ni], accP[mi][ni], 0, 0, 0);
        }

        if (ih) {  // zz complete: fold z (fp32) into output accumulator
            const int zl = s >> 1;
            #pragma unroll
            for (int mi = 0; mi < 2; ++mi) {
                const f32x4 zv = *reinterpret_cast<const f32x4*>(
                    &zlds[zl][wr * 32 + mi * 16 + kg * 4]);
                #pragma unroll
                for (int ni = 0; ni < 4; ++ni) {
                    accO[mi][ni] += zv * accP[mi][ni];
                    accP[mi][ni] = vzero;
                }
            }
        }
        __syncthreads();
        buf ^= 1;
    }

    // epilogue: split-K partial -> fp32 HW atomic add
    // D layout (16x16): row = kg*4 + r, col = r16  (proven in round-1 kernel)
    #pragma unroll
    for (int mi = 0; mi < 2; ++mi) {
        const int rb = bm0 + wr * 32 + mi * 16 + kg * 4;
        #pragma unroll
        for (int ni = 0; ni < 4; ++ni) {
            const int col = n0 + wc * 64 + ni * 16 + r16;
            #pragma unroll
            for (int r = 0; r < 4; ++r)
                unsafeAtomicAdd(&out[(size_t)(rb + r) * OD + col], accO[mi][ni][r]);
        }
    }
}

// ---------------- fallback GEMM (round-1 proven path, if ws too small) ------
constexpr int FBM = 128, FBN = 128, FBK = 64;
constexpr int FSPLITK = 16;
constexpr int FKCH = (ZD * XD) / FSPLITK;

__global__ __launch_bounds__(256, 2)
void bilinear_gemm_fb(const float* __restrict__ x, const float* __restrict__ z,
                      const float* __restrict__ Wk, float* __restrict__ out)
{
    __shared__ unsigned short Alds[FBM][FBK + 8];
    __shared__ unsigned short Blds2[FBN][FBK + 8];

    const int mt = blockIdx.x, nt = blockIdx.y, ks = blockIdx.z;
    const int m0 = mt * FBM, n0 = nt * FBN;
    const int t = threadIdx.x;
    const int lane = t & 63, w = t >> 6;
    const int wm = (w >> 1) * 64, wn = (w & 1) * 64;
    const int r16 = lane & 15, kg = lane >> 4;
    const int ra = t >> 1;
    const int kh = (t & 1) * 32;

    f32x4 acc[4][4] = {};

    for (int kt = 0; kt < FKCH / FBK; ++kt) {
        const int k0 = ks * FKCH + kt * FBK;
        const int zb = k0 >> 8, ib = k0 & 255;
        const float zv = z[(size_t)(m0 + ra) * ZD + zb];
        const float4* xp = reinterpret_cast<const float4*>(
            x + (size_t)(m0 + ra) * XD + ib + kh);
        const float4* bp = reinterpret_cast<const float4*>(
            Wk + (size_t)zb * (OD * XD) + (size_t)(n0 + ra) * XD + ib + kh);

        float xs[32], bs[32];
        #pragma unroll
        for (int j = 0; j < 8; ++j) {
            const float4 a = xp[j]; const float4 b = bp[j];
            xs[4*j+0]=a.x; xs[4*j+1]=a.y; xs[4*j+2]=a.z; xs[4*j+3]=a.w;
            bs[4*j+0]=b.x; bs[4*j+1]=b.y; bs[4*j+2]=b.z; bs[4*j+3]=b.w;
        }
        __syncthreads();
        #pragma unroll
        for (int j = 0; j < 4; ++j) {
            us8 av, bw;
            #pragma unroll
            for (int e = 0; e < 8; ++e) {
                av[e] = f2bf(zv * xs[8*j+e]);
                bw[e] = f2bf(bs[8*j+e]);
            }
            *reinterpret_cast<us8*>(&Alds[ra][kh + 8*j]) = av;
            *reinterpret_cast<us8*>(&Blds2[ra][kh + 8*j]) = bw;
        }
        __syncthreads();
        #pragma unroll
        for (int khalf = 0; khalf < 2; ++khalf) {
            bf16x8 af[4], bfr[4];
            #pragma unroll
            for (int mi = 0; mi < 4; ++mi)
                af[mi] = *reinterpret_cast<const bf16x8*>(
                    &Alds[wm + mi*16 + r16][khalf*32 + kg*8]);
            #pragma unroll
            for (int ni = 0; ni < 4; ++ni)
                bfr[ni] = *reinterpret_cast<const bf16x8*>(
                    &Blds2[wn + ni*16 + r16][khalf*32 + kg*8]);
            #pragma unroll
            for (int mi = 0; mi < 4; ++mi)
                #pragma unroll
                for (int ni = 0; ni < 4; ++ni)
                    acc[mi][ni] = __builtin_amdgcn_mfma_f32_16x16x32_bf16(
                        af[mi], bfr[ni], acc[mi][ni], 0, 0, 0);
        }
    }
    #pragma unroll
    for (int mi = 0; mi < 4; ++mi)
        #pragma unroll
        for (int ni = 0; ni < 4; ++ni)
            #pragma unroll
            for (int r = 0; r < 4; ++r) {
                const int row = m0 + wm + mi*16 + kg*4 + r;
                const int col = n0 + wn + ni*16 + r16;
                unsafeAtomicAdd(&out[(size_t)row * OD + col], acc[mi][ni][r]);
            }
}

extern "C" void kernel_launch(void* const* d_in, const int* in_sizes, int n_in,
                              void* d_out, int out_size, void* d_ws, size_t ws_size,
                              hipStream_t stream) {
    const float* x  = (const float*)d_in[0];
    const float* z  = (const float*)d_in[1];
    const float* Wk = (const float*)d_in[2];
    const float* Wb = (const float*)d_in[3];
    const float* bk = (const float*)d_in[4];
    const float* bb = (const float*)d_in[5];
    float* out = (float*)d_out;

    const size_t WKB_BYTES = (size_t)ZD * OD * XD * 2;   // 33,554,432
    const size_t XB_BYTES  = (size_t)B_DIM * XD * 2;     //  2,097,152

    // bias terms first (also initializes every element of out)
    bilinear_init<<<dim3(B_DIM / IROWS), dim3(256), 0, stream>>>(x, z, Wb, bk, bb, out);

    if (ws_size >= WKB_BYTES + XB_BYTES) {
        unsigned short* Wkb = (unsigned short*)d_ws;
        unsigned short* xb  = (unsigned short*)((char*)d_ws + WKB_BYTES);
        cvt_f32_bf16<<<dim3(8192), dim3(256), 0, stream>>>(Wk, Wkb);
        cvt_f32_bf16<<<dim3(512),  dim3(256), 0, stream>>>(x, xb);
        bilinear_gemm2<<<dim3(64 * 2 * SZ), dim3(256), 0, stream>>>(Wkb, xb, z, out);
    } else {
        bilinear_gemm_fb<<<dim3(B_DIM / FBM, OD / FBN, FSPLITK), dim3(256), 0, stream>>>(
            x, z, Wk, out);
    }
}

// Round 6
// 530.701 us; speedup vs baseline: 1.2524x; 1.0930x over previous
//
#include <hip/hip_runtime.h>
#include <hip/hip_bf16.h>
#include <stdint.h>

// BilinearDense: out[b,o] = sum_{zz,i} z[b,zz] * x[b,i] * Wk[zz, o*256+i]
//                           + x @ Wb-rows + z @ bk + bb
// Refactor: out[b,o] = sum_zz z[b,zz] * P_zz[b,o],  P_zz = sum_i xbf[b,i]*Wkbf[zz,o,i]
//  -> MFMA A-operand is x (constant across zz): kept in REGISTERS, zero staging.
//  -> B (Wk) pre-converted to bf16 in ws, staged via global_load_lds (zero VALU),
//     with T2 XOR-swizzle done as: linear LDS dest + pre-swizzled GLOBAL source
//     + swizzled ds_read offset (rule #21: both-sides-or-neither).
//  -> z folded back per-zz with fp32 scale-accumulate (accuracy).
//  -> SZ=4 split-K: 512 blocks = exactly 2/CU, one scheduling round; each XCD
//     owns one (nt,kc) 4MB B-stream (fits per-XCD L2).

#define B_DIM 4096
#define XD 256
#define ZD 256
#define OD 256

typedef __bf16 bf16x8 __attribute__((ext_vector_type(8)));
typedef float f32x4 __attribute__((ext_vector_type(4)));
typedef unsigned short us8 __attribute__((ext_vector_type(8)));

__device__ __forceinline__ unsigned short f2bf(float f) {
    union { float f; unsigned int u; } v; v.f = f;
    unsigned int r = v.u + 0x7fffu + ((v.u >> 16) & 1u);  // RNE
    return (unsigned short)(r >> 16);
}

#define GLOAD_LDS16(g, l) __builtin_amdgcn_global_load_lds(                      \
    (const __attribute__((address_space(1))) uint32_t*)(uintptr_t)(g),           \
    (__attribute__((address_space(3))) uint32_t*)(uintptr_t)(l), 16, 0, 0)

// ---------------- fp32 -> bf16 convert (exact-fit grids, 8 elems/thread) ----
__global__ __launch_bounds__(256)
void cvt_f32_bf16(const float* __restrict__ in, unsigned short* __restrict__ out) {
    const int i = blockIdx.x * 256 + threadIdx.x;
    const float4* p = reinterpret_cast<const float4*>(in) + (size_t)i * 2;
    const float4 a = p[0], b = p[1];
    us8 o;
    o[0] = f2bf(a.x); o[1] = f2bf(a.y); o[2] = f2bf(a.z); o[3] = f2bf(a.w);
    o[4] = f2bf(b.x); o[5] = f2bf(b.y); o[6] = f2bf(b.z); o[7] = f2bf(b.w);
    *reinterpret_cast<us8*>(out + (size_t)i * 8) = o;
}

// ---------------- init kernel: bias terms (also zero-inits d_out) -----------
constexpr int IROWS = 16;   // 256 blocks -> every CU busy

__global__ __launch_bounds__(256)
void bilinear_init(const float* __restrict__ x, const float* __restrict__ z,
                   const float* __restrict__ Wb, const float* __restrict__ bk,
                   const float* __restrict__ bb, float* __restrict__ out)
{
    __shared__ float zrow[IROWS][ZD];
    __shared__ float xrow[IROWS][XD];
    const int b0 = blockIdx.x * IROWS;
    const int o = threadIdx.x;

    #pragma unroll
    for (int r = 0; r < IROWS; ++r) {
        zrow[r][o] = z[(size_t)(b0 + r) * ZD + o];
        xrow[r][o] = x[(size_t)(b0 + r) * XD + o];
    }
    __syncthreads();

    float acc[IROWS];
    const float bbo = bb[o];
    #pragma unroll
    for (int r = 0; r < IROWS; ++r) acc[r] = bbo;

    for (int zz = 0; zz < ZD; ++zz) {
        const float w = bk[(size_t)zz * OD + o];
        #pragma unroll
        for (int r = 0; r < IROWS; ++r) acc[r] += zrow[r][zz] * w;
    }

    const float4* wp = reinterpret_cast<const float4*>(Wb + (size_t)o * XD);
    for (int i4 = 0; i4 < XD / 4; ++i4) {
        const float4 w = wp[i4];
        #pragma unroll
        for (int r = 0; r < IROWS; ++r) {
            acc[r] += w.x * xrow[r][i4 * 4 + 0] + w.y * xrow[r][i4 * 4 + 1]
                    + w.z * xrow[r][i4 * 4 + 2] + w.w * xrow[r][i4 * 4 + 3];
        }
    }

    #pragma unroll
    for (int r = 0; r < IROWS; ++r)
        out[(size_t)(b0 + r) * OD + o] = acc[r];
}

// ---------------- main GEMM (bf16 path) -------------------------------------
constexpr int BM = 64, BN = 128, BKI = 128;   // BKI = i-elems per stage (half a zz)
constexpr int SZ = 4;                          // split-K chunks over zz
constexpr int ZCH = ZD / SZ;                   // 64 zz per block
constexpr int NSTEP = ZCH * 2;                 // 128 stages
constexpr int ZH = 32;                         // z-tile staged in halves (8 KB)

__global__ __launch_bounds__(256, 2)
void bilinear_gemm2(const unsigned short* __restrict__ Wkb,  // bf16 [ZD][OD*XD]
                    const unsigned short* __restrict__ xb,   // bf16 [B][XD]
                    const float* __restrict__ z,
                    float* __restrict__ out)
{
    __shared__ __align__(16) unsigned short Blds[2][BN * BKI];  // 64 KB, linear+swz
    __shared__ __align__(16) float zlds[ZH][BM];                // 8 KB (half z-tile)

    // XCD-chunked swizzle: 512 blocks, 64 consecutive sw per XCD = one (nt,kc)
    const int bid = blockIdx.x;
    const int sw = (bid & 7) * 64 + (bid >> 3);
    const int mt = sw & 63;
    const int g  = sw >> 6;            // 8 groups = nt(2) x kc(4)
    const int nt = g & 1, kc = g >> 1;
    const int bm0 = mt * BM, n0 = nt * BN, zb0 = kc * ZCH;

    const int t = threadIdx.x, lane = t & 63, w = t >> 6;
    const int wr = w >> 1, wc = w & 1;           // wave tile: 32 m x 64 n
    const int r16 = lane & 15, kg = lane >> 4;

    // ---- z half-tile stage: zlds[zz][row], fp32 ----
    auto stageZ = [&](int zoff) {
        const int row = t >> 2, q = t & 3;       // 4 threads/row, 8 zz each
        const float4* zp = reinterpret_cast<const float4*>(
            z + (size_t)(bm0 + row) * ZD + zb0 + zoff + q * 8);
        const float4 a = zp[0], b = zp[1];
        float v[8] = {a.x, a.y, a.z, a.w, b.x, b.y, b.z, b.w};
        #pragma unroll
        for (int e = 0; e < 8; ++e) zlds[q * 8 + e][row] = v[e];
    };

    // ---- x fragments in registers (constant across all zz) ----
    // 16x16x32 A-frag: lane holds A[row = base + (l&15)][k = (l>>4)*8 + e]
    bf16x8 xf[2][8];
    #pragma unroll
    for (int mi = 0; mi < 2; ++mi) {
        const int row = bm0 + wr * 32 + mi * 16 + r16;
        #pragma unroll
        for (int ks = 0; ks < 8; ++ks)
            xf[mi][ks] = *reinterpret_cast<const bf16x8*>(
                xb + (size_t)row * XD + ks * 32 + kg * 8);
    }

    // ---- B stage: 32 KB tile = 128 o-rows x 128 i (bf16) ----
    // LDS dest LINEAR (global_load_lds requirement); source pre-swizzled so
    // that LDS[p] = B_logical[p ^ ((row&7)<<4)]; read applies the same XOR.
    auto stageB = [&](int s, int buf) {
        const int zz = zb0 + (s >> 1), ih = s & 1;
        const size_t srcBase = (size_t)zz * (OD * XD) + (size_t)n0 * XD + ih * BKI;
        #pragma unroll
        for (int j = 0; j < 8; ++j) {
            const int offu = w * 8192 + j * 1024;          // wave-uniform byte base
            const int off  = offu + lane * 16;             // this lane's dst bytes
            const int row  = off >> 8;                     // 256 B per row
            const int colb = (off & 255) ^ ((row & 7) << 4);  // pre-swizzled src col
            const unsigned short* src = Wkb + srcBase + (size_t)row * XD + (colb >> 1);
            unsigned short* dst = &Blds[buf][0] + (offu >> 1);
            GLOAD_LDS16(src, dst);
        }
    };

    const f32x4 vzero = {0.f, 0.f, 0.f, 0.f};
    f32x4 accP[2][4] = {};
    f32x4 accO[2][4] = {};

    stageZ(0);
    stageB(0, 0);
    __syncthreads();

    int buf = 0;
    for (int s = 0; s < NSTEP; ++s) {
        if (s == NSTEP / 2) stageZ(ZH);             // second z half (post-barrier safe)
        if (s + 1 < NSTEP) stageB(s + 1, buf ^ 1);  // prefetch next stage

        const int ih = s & 1;
        const unsigned short* bp = &Blds[buf][0];
        #pragma unroll
        for (int ks = 0; ks < 4; ++ks) {
            bf16x8 bfv[4];
            #pragma unroll
            for (int ni = 0; ni < 4; ++ni) {
                const int row = wc * 64 + ni * 16 + r16;
                const int cb = (ks * 64 + kg * 16) ^ ((row & 7) << 4);  // swz read
                bfv[ni] = *reinterpret_cast<const bf16x8*>(bp + row * BKI + (cb >> 1));
            }
            #pragma unroll
            for (int mi = 0; mi < 2; ++mi)
                #pragma unroll
                for (int ni = 0; ni < 4; ++ni)
                    accP[mi][ni] = __builtin_amdgcn_mfma_f32_16x16x32_bf16(
                        xf[mi][ih * 4 + ks], bfv[ni], accP[mi][ni], 0, 0, 0);
        }

        if (ih) {  // zz complete: fold z (fp32) into output accumulator
            const int zl = (s >> 1) & (ZH - 1);
            #pragma unroll
            for (int mi = 0; mi < 2; ++mi) {
                const f32x4 zv = *reinterpret_cast<const f32x4*>(
                    &zlds[zl][wr * 32 + mi * 16 + kg * 4]);
                #pragma unroll
                for (int ni = 0; ni < 4; ++ni) {
                    accO[mi][ni] += zv * accP[mi][ni];
                    accP[mi][ni] = vzero;
                }
            }
        }
        __syncthreads();
        buf ^= 1;
    }

    // epilogue: split-K partial -> fp32 HW atomic add
    // D layout (16x16): row = kg*4 + r, col = r16
    #pragma unroll
    for (int mi = 0; mi < 2; ++mi) {
        const int rb = bm0 + wr * 32 + mi * 16 + kg * 4;
        #pragma unroll
        for (int ni = 0; ni < 4; ++ni) {
            const int col = n0 + wc * 64 + ni * 16 + r16;
            #pragma unroll
            for (int r = 0; r < 4; ++r)
                unsafeAtomicAdd(&out[(size_t)(rb + r) * OD + col], accO[mi][ni][r]);
        }
    }
}

// ---------------- fallback GEMM (round-1 proven path, if ws too small) ------
constexpr int FBM = 128, FBN = 128, FBK = 64;
constexpr int FSPLITK = 16;
constexpr int FKCH = (ZD * XD) / FSPLITK;

__global__ __launch_bounds__(256, 2)
void bilinear_gemm_fb(const float* __restrict__ x, const float* __restrict__ z,
                      const float* __restrict__ Wk, float* __restrict__ out)
{
    __shared__ unsigned short Alds[FBM][FBK + 8];
    __shared__ unsigned short Blds2[FBN][FBK + 8];

    const int mt = blockIdx.x, nt = blockIdx.y, ks = blockIdx.z;
    const int m0 = mt * FBM, n0 = nt * FBN;
    const int t = threadIdx.x;
    const int lane = t & 63, w = t >> 6;
    const int wm = (w >> 1) * 64, wn = (w & 1) * 64;
    const int r16 = lane & 15, kg = lane >> 4;
    const int ra = t >> 1;
    const int kh = (t & 1) * 32;

    f32x4 acc[4][4] = {};

    for (int kt = 0; kt < FKCH / FBK; ++kt) {
        const int k0 = ks * FKCH + kt * FBK;
        const int zb = k0 >> 8, ib = k0 & 255;
        const float zv = z[(size_t)(m0 + ra) * ZD + zb];
        const float4* xp = reinterpret_cast<const float4*>(
            x + (size_t)(m0 + ra) * XD + ib + kh);
        const float4* bp = reinterpret_cast<const float4*>(
            Wk + (size_t)zb * (OD * XD) + (size_t)(n0 + ra) * XD + ib + kh);

        float xs[32], bs[32];
        #pragma unroll
        for (int j = 0; j < 8; ++j) {
            const float4 a = xp[j]; const float4 b = bp[j];
            xs[4*j+0]=a.x; xs[4*j+1]=a.y; xs[4*j+2]=a.z; xs[4*j+3]=a.w;
            bs[4*j+0]=b.x; bs[4*j+1]=b.y; bs[4*j+2]=b.z; bs[4*j+3]=b.w;
        }
        __syncthreads();
        #pragma unroll
        for (int j = 0; j < 4; ++j) {
            us8 av, bw;
            #pragma unroll
            for (int e = 0; e < 8; ++e) {
                av[e] = f2bf(zv * xs[8*j+e]);
                bw[e] = f2bf(bs[8*j+e]);
            }
            *reinterpret_cast<us8*>(&Alds[ra][kh + 8*j]) = av;
            *reinterpret_cast<us8*>(&Blds2[ra][kh + 8*j]) = bw;
        }
        __syncthreads();
        #pragma unroll
        for (int khalf = 0; khalf < 2; ++khalf) {
            bf16x8 af[4], bfr[4];
            #pragma unroll
            for (int mi = 0; mi < 4; ++mi)
                af[mi] = *reinterpret_cast<const bf16x8*>(
                    &Alds[wm + mi*16 + r16][khalf*32 + kg*8]);
            #pragma unroll
            for (int ni = 0; ni < 4; ++ni)
                bfr[ni] = *reinterpret_cast<const bf16x8*>(
                    &Blds2[wn + ni*16 + r16][khalf*32 + kg*8]);
            #pragma unroll
            for (int mi = 0; mi < 4; ++mi)
                #pragma unroll
                for (int ni = 0; ni < 4; ++ni)
                    acc[mi][ni] = __builtin_amdgcn_mfma_f32_16x16x32_bf16(
                        af[mi], bfr[ni], acc[mi][ni], 0, 0, 0);
        }
    }
    #pragma unroll
    for (int mi = 0; mi < 4; ++mi)
        #pragma unroll
        for (int ni = 0; ni < 4; ++ni)
            #pragma unroll
            for (int r = 0; r < 4; ++r) {
                const int row = m0 + wm + mi*16 + kg*4 + r;
                const int col = n0 + wn + ni*16 + r16;
                unsafeAtomicAdd(&out[(size_t)row * OD + col], acc[mi][ni][r]);
            }
}

extern "C" void kernel_launch(void* const* d_in, const int* in_sizes, int n_in,
                              void* d_out, int out_size, void* d_ws, size_t ws_size,
                              hipStream_t stream) {
    const float* x  = (const float*)d_in[0];
    const float* z  = (const float*)d_in[1];
    const float* Wk = (const float*)d_in[2];
    const float* Wb = (const float*)d_in[3];
    const float* bk = (const float*)d_in[4];
    const float* bb = (const float*)d_in[5];
    float* out = (float*)d_out;

    const size_t WKB_BYTES = (size_t)ZD * OD * XD * 2;   // 33,554,432
    const size_t XB_BYTES  = (size_t)B_DIM * XD * 2;     //  2,097,152

    // bias terms first (also initializes every element of out)
    bilinear_init<<<dim3(B_DIM / IROWS), dim3(256), 0, stream>>>(x, z, Wb, bk, bb, out);

    if (ws_size >= WKB_BYTES + XB_BYTES) {
        unsigned short* Wkb = (unsigned short*)d_ws;
        unsigned short* xb  = (unsigned short*)((char*)d_ws + WKB_BYTES);
        cvt_f32_bf16<<<dim3(8192), dim3(256), 0, stream>>>(Wk, Wkb);
        cvt_f32_bf16<<<dim3(512),  dim3(256), 0, stream>>>(x, xb);
        bilinear_gemm2<<<dim3(64 * 2 * SZ), dim3(256), 0, stream>>>(Wkb, xb, z, out);
    } else {
        bilinear_gemm_fb<<<dim3(B_DIM / FBM, OD / FBN, FSPLITK), dim3(256), 0, stream>>>(
            x, z, Wk, out);
    }
}

// Round 9
// 272.096 us; speedup vs baseline: 2.4428x; 1.9504x over previous
//
#include <hip/hip_runtime.h>
#include <hip/hip_bf16.h>
#include <stdint.h>

// BilinearDense: out[b,o] = sum_{zz,i} z[b,zz] * x[b,i] * Wk[zz, o*256+i] + biases
// Refactor: out[b,o] = sum_zz z[b,zz] * P_zz[b,o],  P_zz = sum_i xbf[b,i]*Wkbf[zz,o,i]
// r8 -> r9 changes (race + structure):
//  * BM=256 / BN=64 / 8-wave 512-thr blocks / SZ=4 -> 256 blocks = 1/CU.
//    B-traffic (M/BM)*32MB: 2GB -> 512MB (r6 FETCH=595MB showed stream thrash).
//  * Ring: NBUF=4, prefetch depth 2 -> buffer reuse distance = TWO barriers
//    (r8's depth-3 reused one barrier after read -> HW-level stale race).
//  * lgkmcnt(0) drain at every zlds restage handoff (raw s_barrier doesn't
//    drain lgkm; __syncthreads did -> r8's second race window).
//  * Fenced barriers (sched_barrier + memory clobber) kept from r8.
//  * 1 global_load_lds per thread per stage: vmcnt(N) == stages outstanding.

#define B_DIM 4096
#define XD 256
#define ZD 256
#define OD 256

typedef __bf16 bf16x8 __attribute__((ext_vector_type(8)));
typedef float f32x4 __attribute__((ext_vector_type(4)));
typedef unsigned short us8 __attribute__((ext_vector_type(8)));

__device__ __forceinline__ unsigned short f2bf(float f) {
    union { float f; unsigned int u; } v; v.f = f;
    unsigned int r = v.u + 0x7fffu + ((v.u >> 16) & 1u);  // RNE
    return (unsigned short)(r >> 16);
}

#define GLOAD_LDS16(g, l) __builtin_amdgcn_global_load_lds(                      \
    (const __attribute__((address_space(1))) uint32_t*)(uintptr_t)(g),           \
    (__attribute__((address_space(3))) uint32_t*)(uintptr_t)(l), 16, 0, 0)

__device__ __forceinline__ void barrier_fenced() {
    __builtin_amdgcn_s_barrier();
    __builtin_amdgcn_sched_barrier(0);
    asm volatile("" ::: "memory");
}

// ---------------- fp32 -> bf16 convert (exact-fit grids, 8 elems/thread) ----
__global__ __launch_bounds__(256)
void cvt_f32_bf16(const float* __restrict__ in, unsigned short* __restrict__ out) {
    const int i = blockIdx.x * 256 + threadIdx.x;
    const float4* p = reinterpret_cast<const float4*>(in) + (size_t)i * 2;
    const float4 a = p[0], b = p[1];
    us8 o;
    o[0] = f2bf(a.x); o[1] = f2bf(a.y); o[2] = f2bf(a.z); o[3] = f2bf(a.w);
    o[4] = f2bf(b.x); o[5] = f2bf(b.y); o[6] = f2bf(b.z); o[7] = f2bf(b.w);
    *reinterpret_cast<us8*>(out + (size_t)i * 8) = o;
}

// ---------------- init kernel: bias terms (also zero-inits d_out) -----------
constexpr int IROWS = 16;   // 256 blocks -> every CU busy

__global__ __launch_bounds__(256)
void bilinear_init(const float* __restrict__ x, const float* __restrict__ z,
                   const float* __restrict__ Wb, const float* __restrict__ bk,
                   const float* __restrict__ bb, float* __restrict__ out)
{
    __shared__ float zrow[IROWS][ZD];
    __shared__ float xrow[IROWS][XD];
    const int b0 = blockIdx.x * IROWS;
    const int o = threadIdx.x;

    #pragma unroll
    for (int r = 0; r < IROWS; ++r) {
        zrow[r][o] = z[(size_t)(b0 + r) * ZD + o];
        xrow[r][o] = x[(size_t)(b0 + r) * XD + o];
    }
    __syncthreads();

    float acc[IROWS];
    const float bbo = bb[o];
    #pragma unroll
    for (int r = 0; r < IROWS; ++r) acc[r] = bbo;

    for (int zz = 0; zz < ZD; ++zz) {
        const float w = bk[(size_t)zz * OD + o];
        #pragma unroll
        for (int r = 0; r < IROWS; ++r) acc[r] += zrow[r][zz] * w;
    }

    const float4* wp = reinterpret_cast<const float4*>(Wb + (size_t)o * XD);
    for (int i4 = 0; i4 < XD / 4; ++i4) {
        const float4 w = wp[i4];
        #pragma unroll
        for (int r = 0; r < IROWS; ++r) {
            acc[r] += w.x * xrow[r][i4 * 4 + 0] + w.y * xrow[r][i4 * 4 + 1]
                    + w.z * xrow[r][i4 * 4 + 2] + w.w * xrow[r][i4 * 4 + 3];
        }
    }

    #pragma unroll
    for (int r = 0; r < IROWS; ++r)
        out[(size_t)(b0 + r) * OD + o] = acc[r];
}

// ---------------- main GEMM (bf16 path) -------------------------------------
constexpr int BM = 256, BN = 64, BKI = 64;    // BKI = i-elems per stage (1/4 zz)
constexpr int SZ = 4;                          // split-K chunks over zz
constexpr int ZCH = ZD / SZ;                   // 64 zz per block
constexpr int NSTEP = ZCH * 4;                 // 256 stages (4 per zz)
constexpr int ZQ = 16;                         // z-tile staged in quarters (16 KB)
constexpr int NBUF = 4;                        // ring buffers (prefetch depth 2)

// Per-step: 2 k-slices x (2 mi x 4 ni) MFMA on buffer (S_&3).
// Q_ MUST be compile-time (xf/accP are register arrays, rule #20).
#define COMPUTE_STEP(S_, Q_)                                                     \
  {                                                                              \
    const unsigned short* bp = &Blds[(S_) & (NBUF - 1)][0];                      \
    _Pragma("unroll")                                                            \
    for (int ks = 0; ks < 2; ++ks) {                                             \
      bf16x8 bfv[4];                                                             \
      _Pragma("unroll")                                                          \
      for (int ni = 0; ni < 4; ++ni) {                                           \
        const int row = ni * 16 + r16;                                           \
        const int cb = (ks * 64 + kg * 16) ^ ((row & 7) << 4);                   \
        bfv[ni] = *reinterpret_cast<const bf16x8*>(bp + row * BKI + (cb >> 1));  \
      }                                                                          \
      _Pragma("unroll")                                                          \
      for (int mi = 0; mi < 2; ++mi)                                             \
        _Pragma("unroll")                                                        \
        for (int ni = 0; ni < 4; ++ni)                                           \
          accP[mi][ni] = __builtin_amdgcn_mfma_f32_16x16x32_bf16(                \
              xf[mi][(Q_) * 2 + ks], bfv[ni], accP[mi][ni], 0, 0, 0);            \
    }                                                                            \
    if ((Q_) == 3) { /* zz complete: fold z (fp32) into output accumulator */    \
      const int zl = ((S_) >> 2) & (ZQ - 1);                                     \
      _Pragma("unroll")                                                          \
      for (int mi = 0; mi < 2; ++mi) {                                           \
        const f32x4 zv = *reinterpret_cast<const f32x4*>(                        \
            &zlds[zl][w * 32 + mi * 16 + kg * 4]);                               \
        _Pragma("unroll")                                                        \
        for (int ni = 0; ni < 4; ++ni) {                                         \
          accO[mi][ni] += zv * accP[mi][ni];                                     \
          accP[mi][ni] = vzero;                                                  \
        }                                                                        \
      }                                                                          \
    }                                                                            \
  }

__global__ __launch_bounds__(512, 1)
void bilinear_gemm2(const unsigned short* __restrict__ Wkb,  // bf16 [ZD][OD*XD]
                    const unsigned short* __restrict__ xb,   // bf16 [B][XD]
                    const float* __restrict__ z,
                    float* __restrict__ out)
{
    __shared__ __align__(16) unsigned short Blds[NBUF][BN * BKI];  // 4 x 8 KB ring
    __shared__ __align__(16) float zlds[ZQ][BM];                   // 16 KB

    // XCD-chunked swizzle: 256 blocks = 8 XCDs x 32; each XCD owns 2 (nt,kc)
    // groups (2 x 2MB B-slices = 4MB, fits per-XCD L2).
    const int bid = blockIdx.x;
    const int sw = (bid & 7) * 32 + (bid >> 3);
    const int mt = sw & 15;
    const int g  = sw >> 4;            // 16 groups = nt(4) x kc(4)
    const int nt = g & 3, kc = g >> 2;
    const int bm0 = mt * BM, n0 = nt * BN, zb0 = kc * ZCH;

    const int t = threadIdx.x, lane = t & 63, w = t >> 6;   // 8 waves, 8m x 1n
    const int r16 = lane & 15, kg = lane >> 4;

    // ---- z quarter-tile stage: zlds[zz][row], fp32 (512 thr: 2/row) ----
    auto stageZ = [&](int zoff) {
        const int row = t >> 1, q = t & 1;       // 2 threads/row, 8 zz each
        const float4* zp = reinterpret_cast<const float4*>(
            z + (size_t)(bm0 + row) * ZD + zb0 + zoff + q * 8);
        const float4 a = zp[0], b = zp[1];
        float v[8] = {a.x, a.y, a.z, a.w, b.x, b.y, b.z, b.w};
        #pragma unroll
        for (int e = 0; e < 8; ++e) zlds[q * 8 + e][row] = v[e];
    };

    // ---- x fragments in registers (constant across all zz): 64 VGPR ----
    // 16x16x32 A-frag: lane holds A[row = base + (l&15)][k = (l>>4)*8 + e]
    bf16x8 xf[2][8];
    #pragma unroll
    for (int mi = 0; mi < 2; ++mi) {
        const int row = bm0 + w * 32 + mi * 16 + r16;
        #pragma unroll
        for (int ks = 0; ks < 8; ++ks)
            xf[mi][ks] = *reinterpret_cast<const bf16x8*>(
                xb + (size_t)row * XD + ks * 32 + kg * 8);
    }
    // PIN xf (r6: VGPR_Count 88 proved compiler rematerialized these loads).
    #pragma unroll
    for (int mi = 0; mi < 2; ++mi)
        #pragma unroll
        for (int ks = 0; ks < 8; ++ks)
            asm volatile("" : "+v"(*reinterpret_cast<f32x4*>(&xf[mi][ks])));

    // ---- B stage: 8 KB = 64 o-rows x 64 i (bf16), ONE gload_lds/thread ----
    // LDS dest LINEAR; source pre-swizzled so LDS[p] = B[p ^ ((row&7)<<4)];
    // read applies the same XOR (rule #21 both-sides).
    auto stageB = [&](int s, int buf) {
        const int zz = zb0 + (s >> 2), qi = s & 3;
        const size_t srcBase = (size_t)zz * (OD * XD) + (size_t)n0 * XD + qi * BKI;
        const int offu = w * 1024;                      // wave-uniform byte base
        const int off  = offu + lane * 16;              // this lane's dst bytes
        const int row  = off >> 7;                      // 128 B per row
        const int colb = (off & 127) ^ ((row & 7) << 4);
        const unsigned short* src = Wkb + srcBase + (size_t)row * XD + (colb >> 1);
        unsigned short* dst = &Blds[buf][0] + (offu >> 1);
        GLOAD_LDS16(src, dst);
    };

    const f32x4 vzero = {0.f, 0.f, 0.f, 0.f};
    f32x4 accP[2][4] = {};
    f32x4 accO[2][4] = {};

    // ---- prologue: z quarter 0; fill 2 ring slots; stage 0 landed ----
    stageZ(0);
    stageB(0, 0); stageB(1, 1);
    asm volatile("s_waitcnt vmcnt(1) lgkmcnt(0)" ::: "memory");
    barrier_fenced();

    // ---- main loop: depth-2 prefetch, counted vmcnt(1), 2-barrier reuse ----
    // End of step s: stages s+1, s+2 outstanding; vmcnt(1) -> s+1 landed.
    // stageB(s+2) writes the buffer read at step s-2 (TWO barriers ago).
    for (int sb = 0; sb < NSTEP - 4; sb += 4) {
        #pragma unroll
        for (int q = 0; q < 4; ++q) {
            const int s = sb + q;
            stageB(s + 2, (s + 2) & (NBUF - 1));
            // z restage at zz-quarter boundaries (s = 64,128,192; all q==0)
            if (q == 0 && (sb == 64 || sb == 128 || sb == 192)) stageZ(sb >> 2);
            COMPUTE_STEP(s, q);
            // lgkm drain at zlds handoffs: after restage (writes must land
            // before barrier) and at the step BEFORE a restage (old-half
            // reads must complete before next step's overwrite).
            if ((q == 0 && (sb == 64 || sb == 128 || sb == 192)) ||
                (q == 3 && (sb == 60 || sb == 124 || sb == 188)))
                asm volatile("s_waitcnt vmcnt(1) lgkmcnt(0)" ::: "memory");
            else
                asm volatile("s_waitcnt vmcnt(1)" ::: "memory");
            barrier_fenced();
        }
    }

    // ---- peeled tail: s = NSTEP-4 .. NSTEP-1 ----
    {
        stageB(NSTEP - 2, (NSTEP - 2) & (NBUF - 1));
        COMPUTE_STEP(NSTEP - 4, 0);
        asm volatile("s_waitcnt vmcnt(1)" ::: "memory");
        barrier_fenced();
    }
    {
        stageB(NSTEP - 1, (NSTEP - 1) & (NBUF - 1));
        COMPUTE_STEP(NSTEP - 3, 1);
        asm volatile("s_waitcnt vmcnt(1)" ::: "memory");
        barrier_fenced();
    }
    COMPUTE_STEP(NSTEP - 2, 2);
    asm volatile("s_waitcnt vmcnt(0)" ::: "memory");
    barrier_fenced();
    COMPUTE_STEP(NSTEP - 1, 3);

    // ---- epilogue: split-K partial -> fp32 HW atomic add ----
    // D layout (16x16): row = kg*4 + r, col = r16
    #pragma unroll
    for (int mi = 0; mi < 2; ++mi) {
        const int rb = bm0 + w * 32 + mi * 16 + kg * 4;
        #pragma unroll
        for (int ni = 0; ni < 4; ++ni) {
            const int col = n0 + ni * 16 + r16;
            #pragma unroll
            for (int r = 0; r < 4; ++r)
                unsafeAtomicAdd(&out[(size_t)(rb + r) * OD + col], accO[mi][ni][r]);
        }
    }
}

// ---------------- fallback GEMM (round-1 proven path, if ws too small) ------
constexpr int FBM = 128, FBN = 128, FBK = 64;
constexpr int FSPLITK = 16;
constexpr int FKCH = (ZD * XD) / FSPLITK;

__global__ __launch_bounds__(256, 2)
void bilinear_gemm_fb(const float* __restrict__ x, const float* __restrict__ z,
                      const float* __restrict__ Wk, float* __restrict__ out)
{
    __shared__ unsigned short Alds[FBM][FBK + 8];
    __shared__ unsigned short Blds2[FBN][FBK + 8];

    const int mt = blockIdx.x, nt = blockIdx.y, ks = blockIdx.z;
    const int m0 = mt * FBM, n0 = nt * FBN;
    const int t = threadIdx.x;
    const int lane = t & 63, w = t >> 6;
    const int wm = (w >> 1) * 64, wn = (w & 1) * 64;
    const int r16 = lane & 15, kg = lane >> 4;
    const int ra = t >> 1;
    const int kh = (t & 1) * 32;

    f32x4 acc[4][4] = {};

    for (int kt = 0; kt < FKCH / FBK; ++kt) {
        const int k0 = ks * FKCH + kt * FBK;
        const int zb = k0 >> 8, ib = k0 & 255;
        const float zv = z[(size_t)(m0 + ra) * ZD + zb];
        const float4* xp = reinterpret_cast<const float4*>(
            x + (size_t)(m0 + ra) * XD + ib + kh);
        const float4* bp = reinterpret_cast<const float4*>(
            Wk + (size_t)zb * (OD * XD) + (size_t)(n0 + ra) * XD + ib + kh);

        float xs[32], bs[32];
        #pragma unroll
        for (int j = 0; j < 8; ++j) {
            const float4 a = xp[j]; const float4 b = bp[j];
            xs[4*j+0]=a.x; xs[4*j+1]=a.y; xs[4*j+2]=a.z; xs[4*j+3]=a.w;
            bs[4*j+0]=b.x; bs[4*j+1]=b.y; bs[4*j+2]=b.z; bs[4*j+3]=b.w;
        }
        __syncthreads();
        #pragma unroll
        for (int j = 0; j < 4; ++j) {
            us8 av, bw;
            #pragma unroll
            for (int e = 0; e < 8; ++e) {
                av[e] = f2bf(zv * xs[8*j+e]);
                bw[e] = f2bf(bs[8*j+e]);
            }
            *reinterpret_cast<us8*>(&Alds[ra][kh + 8*j]) = av;
            *reinterpret_cast<us8*>(&Blds2[ra][kh + 8*j]) = bw;
        }
        __syncthreads();
        #pragma unroll
        for (int khalf = 0; khalf < 2; ++khalf) {
            bf16x8 af[4], bfr[4];
            #pragma unroll
            for (int mi = 0; mi < 4; ++mi)
                af[mi] = *reinterpret_cast<const bf16x8*>(
                    &Alds[wm + mi*16 + r16][khalf*32 + kg*8]);
            #pragma unroll
            for (int ni = 0; ni < 4; ++ni)
                bfr[ni] = *reinterpret_cast<const bf16x8*>(
                    &Blds2[wn + ni*16 + r16][khalf*32 + kg*8]);
            #pragma unroll
            for (int mi = 0; mi < 4; ++mi)
                #pragma unroll
                for (int ni = 0; ni < 4; ++ni)
                    acc[mi][ni] = __builtin_amdgcn_mfma_f32_16x16x32_bf16(
                        af[mi], bfr[ni], acc[mi][ni], 0, 0, 0);
        }
    }
    #pragma unroll
    for (int mi = 0; mi < 4; ++mi)
        #pragma unroll
        for (int ni = 0; ni < 4; ++ni)
            #pragma unroll
            for (int r = 0; r < 4; ++r) {
                const int row = m0 + wm + mi*16 + kg*4 + r;
                const int col = n0 + wn + ni*16 + r16;
                unsafeAtomicAdd(&out[(size_t)row * OD + col], acc[mi][ni][r]);
            }
}

extern "C" void kernel_launch(void* const* d_in, const int* in_sizes, int n_in,
                              void* d_out, int out_size, void* d_ws, size_t ws_size,
                              hipStream_t stream) {
    const float* x  = (const float*)d_in[0];
    const float* z  = (const float*)d_in[1];
    const float* Wk = (const float*)d_in[2];
    const float* Wb = (const float*)d_in[3];
    const float* bk = (const float*)d_in[4];
    const float* bb = (const float*)d_in[5];
    float* out = (float*)d_out;

    const size_t WKB_BYTES = (size_t)ZD * OD * XD * 2;   // 33,554,432
    const size_t XB_BYTES  = (size_t)B_DIM * XD * 2;     //  2,097,152

    // bias terms first (also initializes every element of out)
    bilinear_init<<<dim3(B_DIM / IROWS), dim3(256), 0, stream>>>(x, z, Wb, bk, bb, out);

    if (ws_size >= WKB_BYTES + XB_BYTES) {
        unsigned short* Wkb = (unsigned short*)d_ws;
        unsigned short* xb  = (unsigned short*)((char*)d_ws + WKB_BYTES);
        cvt_f32_bf16<<<dim3(8192), dim3(256), 0, stream>>>(Wk, Wkb);
        cvt_f32_bf16<<<dim3(512),  dim3(256), 0, stream>>>(x, xb);
        bilinear_gemm2<<<dim3(16 * 4 * SZ), dim3(512), 0, stream>>>(Wkb, xb, z, out);
    } else {
        bilinear_gemm_fb<<<dim3(B_DIM / FBM, OD / FBN, FSPLITK), dim3(256), 0, stream>>>(
            x, z, Wk, out);
    }
}